// Round 1
// baseline (397.227 us; speedup 1.0000x reference)
//
#include <hip/hip_runtime.h>

// SymplecticLayer: 2 leapfrog steps, force = grad of tanh-MLP Hamiltonian (8->128->128->1).
// Fully fused fp8-MFMA kernel: each wave owns 16 batch rows; weights pre-swizzled
// into B-fragment order in LDS (fp8 e4m3); activations round-trip LDS as fp8.
// Scales: d2 stored *16, d1 stored *64 (avoid e4m3 denormals); folded into constants.

typedef float f32x4 __attribute__((ext_vector_type(4)));

#define DT    0.01f
#define S2    16.0f
#define S1    64.0f

__device__ __forceinline__ float fast_tanh(float x) {
#if __has_builtin(__builtin_amdgcn_exp2f) && __has_builtin(__builtin_amdgcn_rcpf)
    // tanh(x) = 1 - 2/(exp2(2x*log2e)+1); safe for |x| < 40
    float e = __builtin_amdgcn_exp2f(x * 2.8853900817779268f);
    return 1.0f - 2.0f * __builtin_amdgcn_rcpf(e + 1.0f);
#else
    return tanhf(x);
#endif
}

__device__ __forceinline__ unsigned char to_fp8(float x) {
    return (unsigned char)(__builtin_amdgcn_cvt_pk_fp8_f32(x, x, 0, false) & 0xff);
}

__global__ __launch_bounds__(256) void hnn_leapfrog_kernel(
    const float* __restrict__ Z, const float* __restrict__ W1,
    const float* __restrict__ B1f, const float* __restrict__ W2,
    const float* __restrict__ B2f, const float* __restrict__ W3,
    float* __restrict__ OUT)
{
    // ---- LDS layout (49,664 B total -> 3 blocks/CU) ----
    __shared__ __align__(16) unsigned char sW1B[8 * 64 * 8];        // 4096: fwd L1 B-frags (K rows 8..31 zero)
    __shared__ __align__(16) unsigned char sW2B[4 * 8 * 64 * 8];    // 16384: fwd L2 B-frags  B[k=j][n=k2]=W2[j][k2]
    __shared__ __align__(16) unsigned char sW2T[4 * 8 * 64 * 8];    // 16384: bwd L2 B-frags  B[k=k2][n=j]=W2[j][k2]
    __shared__ __align__(16) unsigned char sW1T[4 * 64 * 8];        // 2048: bwd L1 B-frags  B[k=j][n=i]=W1[i][j]
    __shared__ __align__(16) unsigned char sACT[4 * 16 * 136];      // 8704: per-wave act tile, row stride 136
    __shared__ __align__(16) float sZ[512];                          // 2048: 64 rows x 8 (q0..3,p0..3)

    const int t   = threadIdx.x;
    const int blk = blockIdx.x;

    // ---- zero-fill W1 frag regions (padded K rows must be finite/zero) ----
    for (int i = t; i < 1024; i += 256) ((int*)sW1B)[i] = 0;
    for (int i = t; i < 512;  i += 256) ((int*)sW1T)[i] = 0;
    __syncthreads();

    // ---- stage W1 (8x128) into both frag layouts ----
    for (int i = t; i < 1024; i += 256) {
        int row = i >> 7, col = i & 127;            // row = input dim i (0..7), col = hidden j
        unsigned char q8 = to_fp8(W1[i]);
        // fwd: B[k=row][n=col]; k<8 -> quad=0, j=row
        sW1B[((col >> 4) * 64 + (col & 15)) * 8 + row] = q8;
        // bwd: B[k=col][n=row]
        sW1T[(((col >> 5)) * 64 + ((col >> 3) & 3) * 16 + row) * 8 + (col & 7)] = q8;
    }
    // ---- stage W2 (128x128) into both frag layouts (one coalesced read, two scattered b8 writes) ----
    for (int i = t; i < 4096; i += 256) {
        f32x4 w = ((const f32x4*)W2)[i];
        int base = i * 4;
        int row = base >> 7;                         // j (h1 index)
        int col0 = base & 127;                       // k2 (h2 index)
        #pragma unroll
        for (int u = 0; u < 4; u++) {
            int col = col0 + u;
            unsigned char q8 = to_fp8(w[u]);
            sW2B[(((row >> 5) * 8 + (col >> 4)) * 64 + ((row >> 3) & 3) * 16 + (col & 15)) * 8 + (row & 7)] = q8;
            sW2T[(((col >> 5) * 8 + (row >> 4)) * 64 + ((col >> 3) & 3) * 16 + (row & 15)) * 8 + (col & 7)] = q8;
        }
    }
    // ---- stage z tile (64 rows x 8) ----
    sZ[t]       = Z[blk * 512 + t];
    sZ[t + 256] = Z[blk * 512 + 256 + t];
    __syncthreads();
    // No further block barriers: each wave works on private LDS slices.

    const int lane = t & 63;
    const int wv   = t >> 6;
    const int nn   = lane & 15;       // C-layout column / A-frag row
    const int qd   = lane >> 4;       // quad
    unsigned char* act = sACT + wv * 2176;
    float* zrow = sZ + wv * 128;      // wave's 16 rows x 8 floats

    // per-lane bias/W3 values (column nt*16+nn); S2 folded into w3
    float b1v[8], b2v[8], w3v[8];
    #pragma unroll
    for (int nt = 0; nt < 8; nt++) {
        b1v[nt] = B1f[nt * 16 + nn];
        b2v[nt] = B2f[nt * 16 + nn];
        w3v[nt] = W3[nt * 16 + nn] * S2;
    }

    const unsigned char* actr = act + nn * 136 + qd * 8;   // A-frag read base (row nn)
    unsigned char* actw = act + (qd * 4) * 136 + nn;       // C-layout write base

    #pragma unroll 1
    for (int ev = 0; ev < 4; ev++) {
        // ================= L1 forward: h1 = tanh(z @ W1 + b1) =================
        long long az = 0;
        if (qd == 0) {
            const float* zr = zrow + nn * 8;
            float zv[8];
            #pragma unroll
            for (int j = 0; j < 8; j++) zv[j] = zr[j];
            int lo = __builtin_amdgcn_cvt_pk_fp8_f32(zv[0], zv[1], 0, false);
            lo     = __builtin_amdgcn_cvt_pk_fp8_f32(zv[2], zv[3], lo, true);
            int hi = __builtin_amdgcn_cvt_pk_fp8_f32(zv[4], zv[5], 0, false);
            hi     = __builtin_amdgcn_cvt_pk_fp8_f32(zv[6], zv[7], hi, true);
            az = ((long long)(unsigned)hi << 32) | (unsigned)lo;
        }
        float hc[8][4];   // h1 in C-layout registers (kept for backward factor)
        #pragma unroll
        for (int nt = 0; nt < 8; nt++) {
            long long bf = *(const long long*)(sW1B + nt * 512 + lane * 8);
            f32x4 c = __builtin_amdgcn_mfma_f32_16x16x32_fp8_fp8(az, bf, (f32x4){0.f,0.f,0.f,0.f}, 0, 0, 0);
            #pragma unroll
            for (int r = 0; r < 4; r++) {
                float h = fast_tanh(c[r] + b1v[nt]);
                hc[nt][r] = h;
                actw[r * 136 + nt * 16] = to_fp8(h);
            }
        }
        // ================= L2 forward: d2 = W3*(1-tanh^2(h1@W2+b2)) (*S2) =================
        long long af[4];
        #pragma unroll
        for (int kt = 0; kt < 4; kt++) af[kt] = *(const long long*)(actr + kt * 32);
        #pragma unroll
        for (int nt = 0; nt < 8; nt++) {
            f32x4 c = {0.f, 0.f, 0.f, 0.f};
            #pragma unroll
            for (int kt = 0; kt < 4; kt++) {
                long long bf = *(const long long*)(sW2B + (kt * 8 + nt) * 512 + lane * 8);
                c = __builtin_amdgcn_mfma_f32_16x16x32_fp8_fp8(af[kt], bf, c, 0, 0, 0);
            }
            #pragma unroll
            for (int r = 0; r < 4; r++) {
                float tt = fast_tanh(c[r] + b2v[nt]);
                float d2 = w3v[nt] * (1.0f - tt * tt);     // scaled by S2
                actw[r * 136 + nt * 16] = to_fp8(d2);      // overwrite h1 (already consumed)
            }
        }
        // ================= L2 backward: d1 = (1-h1^2) * (d2 @ W2^T) (*S1) =================
        #pragma unroll
        for (int kt = 0; kt < 4; kt++) af[kt] = *(const long long*)(actr + kt * 32);
        #pragma unroll
        for (int nt = 0; nt < 8; nt++) {
            f32x4 c = {0.f, 0.f, 0.f, 0.f};
            #pragma unroll
            for (int kt = 0; kt < 4; kt++) {
                long long bf = *(const long long*)(sW2T + (kt * 8 + nt) * 512 + lane * 8);
                c = __builtin_amdgcn_mfma_f32_16x16x32_fp8_fp8(af[kt], bf, c, 0, 0, 0);
            }
            #pragma unroll
            for (int r = 0; r < 4; r++) {
                float h = hc[nt][r];
                float d1 = c[r] * (1.0f - h * h) * (S1 / S2);
                actw[r * 136 + nt * 16] = to_fp8(d1);
            }
        }
        // ================= L1 backward: g = d1 @ W1^T  (cols 0..7 valid) =================
        #pragma unroll
        for (int kt = 0; kt < 4; kt++) af[kt] = *(const long long*)(actr + kt * 32);
        f32x4 g = {0.f, 0.f, 0.f, 0.f};
        #pragma unroll
        for (int kt = 0; kt < 4; kt++) {
            long long bf = *(const long long*)(sW1T + kt * 512 + lane * 8);
            g = __builtin_amdgcn_mfma_f32_16x16x32_fp8_fp8(af[kt], bf, g, 0, 0, 0);
        }
        // ================= symplectic update (C-layout: col nn, rows qd*4+r) =================
        const bool first = (ev & 1) == 0;
        if (nn < 4) {
            // dHdq component nn -> p update: p -= 0.5*DT*g
            float* p = zrow + qd * 32 + nn + 4;
            #pragma unroll
            for (int r = 0; r < 4; r++) p[r * 8] -= (0.5f * DT / S1) * g[r];
        } else if (nn < 8 && first) {
            // dHdp component nn-4 -> q update: q += DT*g
            float* p = zrow + qd * 32 + (nn - 4);
            #pragma unroll
            for (int r = 0; r < 4; r++) p[r * 8] += (DT / S1) * g[r];
        }
    }

    // ---- write back (coalesced per wave) ----
    OUT[blk * 512 + wv * 128 + lane]      = zrow[lane];
    OUT[blk * 512 + wv * 128 + 64 + lane] = zrow[64 + lane];
}

extern "C" void kernel_launch(void* const* d_in, const int* in_sizes, int n_in,
                              void* d_out, int out_size, void* d_ws, size_t ws_size,
                              hipStream_t stream) {
    const float* Z  = (const float*)d_in[0];
    const float* W1 = (const float*)d_in[1];
    const float* B1 = (const float*)d_in[2];
    const float* W2 = (const float*)d_in[3];
    const float* B2 = (const float*)d_in[4];
    const float* W3 = (const float*)d_in[5];
    float* OUT = (float*)d_out;
    int blocks = in_sizes[0] / 512;   // 64 batch rows per block
    hipLaunchKernelGGL(hnn_leapfrog_kernel, dim3(blocks), dim3(256), 0, stream,
                       Z, W1, B1, W2, B2, W3, OUT);
}